// Round 6
// baseline (1616.990 us; speedup 1.0000x reference)
//
#include <hip/hip_runtime.h>
#include <cstdint>
#include <cstddef>

#define TT 512
#define BB 64
#define HH 256
#define NG 1024
#define DI 768
#define KY 32

#define LDP 56   // kgemm2 LDS pitch (bf16 elems)

typedef __attribute__((ext_vector_type(8))) short bfrag_t;
typedef __attribute__((ext_vector_type(4))) float f4_t;

__device__ __forceinline__ float sigf(float x) {
    return __fdividef(1.f, 1.f + __expf(-x));
}
__device__ __forceinline__ float tanhfast(float x) {
    return fmaf(2.f, sigf(2.f * x), -1.f);
}
// Masked state mix — SINGLE definition used at BOTH producer and consumer
// sites so the generated ops (and therefore the bits) are identical in all
// 4 partner WGs. h_out = hn*mi + hold*(1-mi), fixed as fma(hn,mi, hold*(1-mi)).
__device__ __forceinline__ float hmix(float hn, float hold, float mi) {
    return fmaf(hn, mi, hold * (1.f - mi));
}
__device__ __forceinline__ unsigned short bf_hi(float x) {
    return (unsigned short)(__float_as_uint(x) >> 16);
}
__device__ __forceinline__ float bf_hi_f(float x) {
    return __uint_as_float(__float_as_uint(x) & 0xffff0000u);
}

// ---------------------------------------------------------------------------
// kgemm2: G_pre = A @ B^T + bias via split-bf16 MFMA (hh+hl+lh).
// ---------------------------------------------------------------------------
__global__ __launch_bounds__(256) void kgemm2(
    const float* __restrict__ sents, const float* __restrict__ Wih,
    const float* __restrict__ bih, const float* __restrict__ bhh,
    float* __restrict__ gpre, int t0)
{
    __shared__ unsigned short Ah[128 * LDP], Al[128 * LDP];
    __shared__ unsigned short Bh[128 * LDP], Bl[128 * LDP];

    const int tid = threadIdx.x;
    const int nb = blockIdx.x;
    const int mb = blockIdx.y;
    const int wv = tid >> 6, lane = tid & 63;
    const int wm = (wv >> 1) * 64, wn = (wv & 1) * 64;
    const int fl = lane & 15, quad = lane >> 4;

    f4_t acc[4][4];
#pragma unroll
    for (int mi = 0; mi < 4; ++mi)
#pragma unroll
        for (int ni = 0; ni < 4; ++ni) acc[mi][ni] = (f4_t)0.f;

    const int sr = tid >> 1, sk = (tid & 1) * 16;
    const int gr = mb * 128 + sr;
    const float* aptr = sents + ((size_t)(gr & 63) * TT + t0 + (gr >> 6)) * DI + sk;
    const float* bptr = Wih + (size_t)(nb * 128 + sr) * 800 + KY + sk;

    for (int k0 = 0; k0 < DI; k0 += 32) {
        float4 av[4], bv[4];
#pragma unroll
        for (int i = 0; i < 4; ++i) {
            av[i] = *(const float4*)(aptr + k0 + i * 4);
            bv[i] = *(const float4*)(bptr + k0 + i * 4);
        }
        __syncthreads();
#pragma unroll
        for (int i = 0; i < 4; ++i) {
            ushort4 h4, l4;
            h4.x = bf_hi(av[i].x); l4.x = bf_hi(av[i].x - bf_hi_f(av[i].x));
            h4.y = bf_hi(av[i].y); l4.y = bf_hi(av[i].y - bf_hi_f(av[i].y));
            h4.z = bf_hi(av[i].z); l4.z = bf_hi(av[i].z - bf_hi_f(av[i].z));
            h4.w = bf_hi(av[i].w); l4.w = bf_hi(av[i].w - bf_hi_f(av[i].w));
            *(ushort4*)&Ah[sr * LDP + sk + i * 4] = h4;
            *(ushort4*)&Al[sr * LDP + sk + i * 4] = l4;
            h4.x = bf_hi(bv[i].x); l4.x = bf_hi(bv[i].x - bf_hi_f(bv[i].x));
            h4.y = bf_hi(bv[i].y); l4.y = bf_hi(bv[i].y - bf_hi_f(bv[i].y));
            h4.z = bf_hi(bv[i].z); l4.z = bf_hi(bv[i].z - bf_hi_f(bv[i].z));
            h4.w = bf_hi(bv[i].w); l4.w = bf_hi(bv[i].w - bf_hi_f(bv[i].w));
            *(ushort4*)&Bh[sr * LDP + sk + i * 4] = h4;
            *(ushort4*)&Bl[sr * LDP + sk + i * 4] = l4;
        }
        __syncthreads();

        bfrag_t ah[4], al2[4], bh[4], bl2[4];
#pragma unroll
        for (int mi = 0; mi < 4; ++mi) {
            int row = wm + mi * 16 + fl;
            ah[mi]  = *(const bfrag_t*)&Ah[row * LDP + quad * 8];
            al2[mi] = *(const bfrag_t*)&Al[row * LDP + quad * 8];
        }
#pragma unroll
        for (int ni = 0; ni < 4; ++ni) {
            int col = wn + ni * 16 + fl;
            bh[ni]  = *(const bfrag_t*)&Bh[col * LDP + quad * 8];
            bl2[ni] = *(const bfrag_t*)&Bl[col * LDP + quad * 8];
        }
#pragma unroll
        for (int mi = 0; mi < 4; ++mi)
#pragma unroll
            for (int ni = 0; ni < 4; ++ni) {
                acc[mi][ni] = __builtin_amdgcn_mfma_f32_16x16x32_bf16(
                    ah[mi], bh[ni], acc[mi][ni], 0, 0, 0);
                acc[mi][ni] = __builtin_amdgcn_mfma_f32_16x16x32_bf16(
                    ah[mi], bl2[ni], acc[mi][ni], 0, 0, 0);
                acc[mi][ni] = __builtin_amdgcn_mfma_f32_16x16x32_bf16(
                    al2[mi], bh[ni], acc[mi][ni], 0, 0, 0);
            }
    }

#pragma unroll
    for (int ni = 0; ni < 4; ++ni) {
        int gcol = nb * 128 + wn + ni * 16 + fl;
        float bias = bih[gcol] + bhh[gcol];
#pragma unroll
        for (int mi = 0; mi < 4; ++mi) {
            int grow = mb * 128 + wm + mi * 16 + quad * 4;
#pragma unroll
            for (int r = 0; r < 4; ++r)
                gpre[(size_t)(grow + r) * NG + gcol] = acc[mi][ni][r] + bias;
        }
    }
}

// ---------------------------------------------------------------------------
// Kernel S: SHi[tl][b][k] = sents[b][t0+tl][:] @ Waff[k][256:1024]^T + baff[k]
// ---------------------------------------------------------------------------
__global__ __launch_bounds__(256) void kshi(
    const float* __restrict__ sents, const float* __restrict__ Waff,
    const float* __restrict__ baff, float* __restrict__ shi, int t0)
{
    const int tid = threadIdx.x;
    const int lane = tid & 63;
    const int r = blockIdx.x * 4 + (tid >> 6);
    const int b = r & 63, tl = r >> 6;
    const float* hi = sents + ((size_t)b * TT + t0 + tl) * DI;
    float p0 = 0.f, p1 = 0.f;
#pragma unroll
    for (int kk = 0; kk < 12; ++kk) {
        int k = kk * 64 + lane;
        float x = hi[k];
        p0 = fmaf(x, Waff[HH + k], p0);
        p1 = fmaf(x, Waff[NG + HH + k], p1);
    }
#pragma unroll
    for (int off = 32; off >= 1; off >>= 1) {
        p0 += __shfl_xor(p0, off, 64);
        p1 += __shfl_xor(p1, off, 64);
    }
    if (lane == 0) {
        shi[(size_t)r * 2 + 0] = p0 + baff[0];
        shi[(size_t)r * 2 + 1] = p1 + baff[1];
    }
}

// ---------------------------------------------------------------------------
// init: zero hbox (32768 words) + pbox (8192 words) — contiguous, 40960 u64
// ---------------------------------------------------------------------------
__global__ void kinit(unsigned long long* __restrict__ box) {
    box[(size_t)blockIdx.x * 512 + threadIdx.x] = 0ull;
}

// ---------------------------------------------------------------------------
// krec4: 4-way-split recurrence, single-barrier step.
//  - hn words AND per-wave score-partial words published in parallel
//    (packed f32<<32 | t+1, relaxed agent atomics, parity double-buffer).
//  - partner h-state held in consumer registers (hpreg); producers in hreg.
//    h_out mix via shared hmix() -> bit-identical across all 4 WGs.
//  - wave 3 polls 4x16 partial words, xor-tree reduces (fixed order),
//    writes redP[4][2]; post-barrier everyone sums 4 terms + shi -> pred.
//  - hk double-buffered by parity: matvec reads hk[p], writers write hk[p^1].
// ---------------------------------------------------------------------------
__global__ __launch_bounds__(512, 1) void krec4(
    const float* __restrict__ gpre,   // [Tc][64][1024]
    const float* __restrict__ shi,    // [Tc][64][2]
    const float* __restrict__ Whh,    // [1024][256]
    const float* __restrict__ mask,   // [64][512]
    float* __restrict__ out,          // [64][512][2]
    float* __restrict__ sh, float* __restrict__ sc, int* __restrict__ sp,
    unsigned long long* __restrict__ hbox,  // [2][64][4][64]
    unsigned long long* __restrict__ pbox,  // [2][64][4][8][2]
    const float* __restrict__ Wih, const float* __restrict__ tag,
    const float* __restrict__ Waff,
    int t0, int Tc, int first)
{
    const int blk = blockIdx.x;
    const int g = blk >> 6, b = blk & 63;
    const int tid = threadIdx.x;
    const int w = tid >> 6, lane = tid & 63;
    const int jl = lane & 7, kq = lane >> 3;
    const int jh = w * 8 + jl;
    const int jglob = g * 64 + jh;
    const int pg = (g + 1 + w) & 3;       // hn partner for waves 0..2

    __shared__ float hk[2][8 * 36];       // double-buffered h, K-octant layout
    __shared__ float P[2][4][64];
    __shared__ float tg[2][KY];
    __shared__ float redP[4][2];

    float4 wreg[4][8];
#pragma unroll
    for (int gt = 0; gt < 4; ++gt) {
        const float4* src = (const float4*)(Whh + (size_t)(gt * HH + jglob) * HH + kq * 32);
#pragma unroll
        for (int kk = 0; kk < 8; ++kk) wreg[gt][kk] = src[kk];
    }
    const float waff0 = Waff[jglob];
    const float waff1 = Waff[NG + jglob];

    if (tid < 2 * KY) tg[tid >> 5][tid & 31] = tag[tid];
    __syncthreads();
    {   // P[r][gt][j2] = tag_em[r] @ Wih[gt*256 + 64g + j2][0:32]^T
        int r = tid >> 8, rem = tid & 255, gt = rem >> 6, j2 = rem & 63;
        int row = gt * HH + g * 64 + j2;
        const float4* wr = (const float4*)(Wih + (size_t)row * 800);
        float s = 0.f;
#pragma unroll
        for (int kk = 0; kk < 8; ++kk) {
            float4 v = wr[kk];
            s = fmaf(v.x, tg[r][kk * 4 + 0], s);
            s = fmaf(v.y, tg[r][kk * 4 + 1], s);
            s = fmaf(v.z, tg[r][kk * 4 + 2], s);
            s = fmaf(v.w, tg[r][kk * 4 + 3], s);
        }
        P[r][gt][j2] = s;
    }

    const int p0i = t0 & 1;
    float creg, hreg = 0.f, hpreg = 0.f; int pred;
    if (first) {
        creg = 0.f; pred = -1;
        if (tid < HH) hk[p0i][(tid >> 5) * 36 + (tid & 31)] = 0.f;
    } else {
        creg = sc[(size_t)b * HH + jglob];
        pred = sp[b];
        hreg = sh[(size_t)b * HH + jglob];          // used by kq==0 lanes
        if (tid < 192) hpreg = sh[(size_t)b * HH + pg * 64 + lane];
        if (tid < HH) hk[p0i][(tid >> 5) * 36 + (tid & 31)] = sh[(size_t)b * HH + tid];
    }
    __syncthreads();

    // prefetched current-step operands
    float cgp0, cgp1, cgp2, cgp3, cmi, cs0, cs1;
    {
        const float* gp = gpre + (size_t)b * NG;
        cgp0 = gp[0 * HH + jglob]; cgp1 = gp[1 * HH + jglob];
        cgp2 = gp[2 * HH + jglob]; cgp3 = gp[3 * HH + jglob];
        cmi = mask[(size_t)b * TT + t0];
        const float* s2 = shi + (size_t)b * 2;
        cs0 = s2[0]; cs1 = s2[1];
    }

    for (int tl = 0; tl < Tc; ++tl) {
        const int t = t0 + tl;
        const int p = t & 1;
        const unsigned cnt = (unsigned)(t + 1);
        const float* hkr = hk[p];
        float* hkw = hk[p ^ 1];

        float pv0 = 0.f, pv1 = 0.f, pv2 = 0.f, pv3 = 0.f;
        if (pred >= 0) {
            pv0 = P[pred][0][jh]; pv1 = P[pred][1][jh];
            pv2 = P[pred][2][jh]; pv3 = P[pred][3][jh];
        }

        // ---- matvec over K-octant [32kq, 32kq+32) ----
        float a0 = 0.f, a1 = 0.f, a2 = 0.f, a3 = 0.f;
        const float4* h4 = (const float4*)(hkr + kq * 36);
#pragma unroll
        for (int kk = 0; kk < 8; ++kk) {
            float4 hv = h4[kk];
            a0 = fmaf(wreg[0][kk].x, hv.x, a0); a0 = fmaf(wreg[0][kk].y, hv.y, a0);
            a0 = fmaf(wreg[0][kk].z, hv.z, a0); a0 = fmaf(wreg[0][kk].w, hv.w, a0);
            a1 = fmaf(wreg[1][kk].x, hv.x, a1); a1 = fmaf(wreg[1][kk].y, hv.y, a1);
            a1 = fmaf(wreg[1][kk].z, hv.z, a1); a1 = fmaf(wreg[1][kk].w, hv.w, a1);
            a2 = fmaf(wreg[2][kk].x, hv.x, a2); a2 = fmaf(wreg[2][kk].y, hv.y, a2);
            a2 = fmaf(wreg[2][kk].z, hv.z, a2); a2 = fmaf(wreg[2][kk].w, hv.w, a2);
            a3 = fmaf(wreg[3][kk].x, hv.x, a3); a3 = fmaf(wreg[3][kk].y, hv.y, a3);
            a3 = fmaf(wreg[3][kk].z, hv.z, a3); a3 = fmaf(wreg[3][kk].w, hv.w, a3);
        }
        a0 += __shfl_xor(a0, 8, 64); a0 += __shfl_xor(a0, 16, 64); a0 += __shfl_xor(a0, 32, 64);
        a1 += __shfl_xor(a1, 8, 64); a1 += __shfl_xor(a1, 16, 64); a1 += __shfl_xor(a1, 32, 64);
        a2 += __shfl_xor(a2, 8, 64); a2 += __shfl_xor(a2, 16, 64); a2 += __shfl_xor(a2, 32, 64);
        a3 += __shfl_xor(a3, 8, 64); a3 += __shfl_xor(a3, 16, 64); a3 += __shfl_xor(a3, 32, 64);

        float gi = a0 + cgp0 + pv0;
        float gf = a1 + cgp1 + pv1;
        float gg = a2 + cgp2 + pv2;
        float go = a3 + cgp3 + pv3;
        float ig = sigf(gi), fg = sigf(gf);
        float g2 = tanhfast(gg), og = sigf(go);
        float cn = fmaf(fg, creg, ig * g2);
        float hn = og * tanhfast(cn);        // identical across the 8 kq replicas
        const float mi = cmi;
        const float s2v0 = cs0, s2v1 = cs1;
        creg = cn * mi + creg * (1.f - mi);

        // ---- publish own hn + update own h state ----
        if (kq == 0) {
            unsigned long long wd =
                ((unsigned long long)__float_as_uint(hn) << 32) | cnt;
            __hip_atomic_store(&hbox[((size_t)(p * BB + b) * 4 + g) * 64 + jh], wd,
                               __ATOMIC_RELAXED, __HIP_MEMORY_SCOPE_AGENT);
            hreg = hmix(hn, hreg, mi);
            hkw[(jglob >> 5) * 36 + (jglob & 31)] = hreg;
        }
        // ---- per-wave score partial over this wave's 8 own dims ----
        float sp0 = hn * waff0, sp1 = hn * waff1;
        sp0 += __shfl_xor(sp0, 1, 64); sp1 += __shfl_xor(sp1, 1, 64);
        sp0 += __shfl_xor(sp0, 2, 64); sp1 += __shfl_xor(sp1, 2, 64);
        sp0 += __shfl_xor(sp0, 4, 64); sp1 += __shfl_xor(sp1, 4, 64);
        if (lane == 0) {
            unsigned long long* pb =
                &pbox[(((size_t)(p * BB + b) * 4 + g) * 8 + w) * 2];
            unsigned long long w0 =
                ((unsigned long long)__float_as_uint(sp0) << 32) | cnt;
            unsigned long long w1 =
                ((unsigned long long)__float_as_uint(sp1) << 32) | cnt;
            __hip_atomic_store(&pb[0], w0, __ATOMIC_RELAXED, __HIP_MEMORY_SCOPE_AGENT);
            __hip_atomic_store(&pb[1], w1, __ATOMIC_RELAXED, __HIP_MEMORY_SCOPE_AGENT);
        }

        // ---- prefetch next step's operands (hidden under the polls) ----
        if (tl + 1 < Tc) {
            const float* gp2 = gpre + ((size_t)(tl + 1) * BB + b) * NG;
            cgp0 = gp2[0 * HH + jglob]; cgp1 = gp2[1 * HH + jglob];
            cgp2 = gp2[2 * HH + jglob]; cgp3 = gp2[3 * HH + jglob];
            cmi = mask[(size_t)b * TT + t + 1];
            const float* s2n = shi + ((size_t)(tl + 1) * BB + b) * 2;
            cs0 = s2n[0]; cs1 = s2n[1];
        }

        // ---- consume: partner hn (waves 0-2) / score partials (wave 3) ----
        if (tid < 192) {
            const unsigned long long* wp =
                &hbox[((size_t)(p * BB + b) * 4 + pg) * 64 + lane];
            unsigned long long wv;
            do {
                wv = __hip_atomic_load(wp, __ATOMIC_RELAXED, __HIP_MEMORY_SCOPE_AGENT);
            } while ((unsigned)wv != cnt);
            float v = __uint_as_float((unsigned)(wv >> 32));
            hpreg = hmix(v, hpreg, mi);
            int kf = pg * 64 + lane;
            hkw[(kf >> 5) * 36 + (kf & 31)] = hpreg;
        } else if (tid < 256) {
            int gg = lane >> 4, idx = lane & 15;
            int sl = (g + gg) & 3;
            const unsigned long long* wp =
                &pbox[(((size_t)(p * BB + b) * 4 + sl) * 8 + (idx >> 1)) * 2 + (idx & 1)];
            unsigned long long wv;
            do {
                wv = __hip_atomic_load(wp, __ATOMIC_RELAXED, __HIP_MEMORY_SCOPE_AGENT);
            } while ((unsigned)wv != cnt);
            float v = __uint_as_float((unsigned)(wv >> 32));
            // xor-tree over the 8 wave-partials (fixed order, same in all WGs)
            v += __shfl_xor(v, 2, 64);
            v += __shfl_xor(v, 4, 64);
            v += __shfl_xor(v, 8, 64);
            if (idx < 2) redP[sl][idx] = v;
        }
        __syncthreads();   // B3: hk[p^1] + redP complete

        // ---- total score, fixed order -> bit-identical pred in all 4 WGs ----
        float q0 = ((redP[0][0] + redP[1][0]) + redP[2][0]) + redP[3][0];
        float q1 = ((redP[0][1] + redP[1][1]) + redP[2][1]) + redP[3][1];
        float ts0 = q0 + s2v0, ts1 = q1 + s2v1;
        pred = (ts1 > ts0) ? 1 : 0;
        if (g == 0 && tid == 0) {
            float m = fmaxf(ts0, ts1);
            float lse = m + log1pf(expf(-fabsf(ts0 - ts1)));
            float* op = out + ((size_t)b * TT + t) * 2;
            op[0] = ts0 - lse; op[1] = ts1 - lse;
        }
    }

    if (kq == 0) {
        sh[(size_t)b * HH + jglob] = hreg;
        sc[(size_t)b * HH + jglob] = creg;
    }
    if (g == 0 && tid == 0) sp[b] = pred;
}

// ---------------------------------------------------------------------------
extern "C" void kernel_launch(void* const* d_in, const int* in_sizes, int n_in,
                              void* d_out, int out_size, void* d_ws, size_t ws_size,
                              hipStream_t stream) {
    (void)in_sizes; (void)n_in; (void)out_size;
    const float* sents = (const float*)d_in[0];
    const float* mask  = (const float*)d_in[1];
    const float* Wih   = (const float*)d_in[2];
    const float* Whh   = (const float*)d_in[3];
    const float* bih   = (const float*)d_in[4];
    const float* bhh   = (const float*)d_in[5];
    const float* Waff  = (const float*)d_in[6];
    const float* baff  = (const float*)d_in[7];
    const float* tag   = (const float*)d_in[8];
    float* out = (float*)d_out;

    const size_t fixed = (size_t)BB * HH * 4 * 2          // sh, sc
                       + BB * 4                            // sp
                       + (size_t)2 * BB * 4 * 64 * 8      // hbox
                       + (size_t)2 * BB * 4 * 8 * 2 * 8   // pbox
                       + 4096;
    int Tc = 8;
    const int cands[7] = {512, 256, 128, 64, 32, 16, 8};
    for (int i = 0; i < 7; ++i) {
        size_t need = (size_t)cands[i] * BB * NG * 4
                    + (size_t)cands[i] * BB * 2 * 4
                    + fixed;
        if (need <= ws_size) { Tc = cands[i]; break; }
    }

    char* wsp = (char*)d_ws;
    float* gpre = (float*)wsp; wsp += (size_t)Tc * BB * NG * 4;
    float* shiw = (float*)wsp; wsp += (size_t)Tc * BB * 2 * 4;
    float* shst = (float*)wsp; wsp += (size_t)BB * HH * 4;
    float* scst = (float*)wsp; wsp += (size_t)BB * HH * 4;
    int*   spst = (int*)wsp;   wsp += BB * 4;
    unsigned long long* hbox = (unsigned long long*)wsp; wsp += (size_t)2 * BB * 4 * 64 * 8;
    unsigned long long* pbox = (unsigned long long*)wsp;

    // hbox (32768) + pbox (8192) are contiguous: zero 40960 words
    kinit<<<dim3(80), 512, 0, stream>>>(hbox);

    const int nch = TT / Tc;
    for (int c = 0; c < nch; ++c) {
        const int t0 = c * Tc;
        kgemm2<<<dim3(8, Tc * 64 / 128), 256, 0, stream>>>(sents, Wih, bih, bhh, gpre, t0);
        kshi<<<dim3(Tc * 16), 256, 0, stream>>>(sents, Waff, baff, shiw, t0);
        krec4<<<dim3(256), 512, 0, stream>>>(gpre, shiw, Whh, mask, out,
                                             shst, scst, spst, hbox, pbox,
                                             Wih, tag, Waff, t0, Tc, (c == 0) ? 1 : 0);
    }
}